// Round 3
// baseline (333.370 us; speedup 1.0000x reference)
//
#include <hip/hip_runtime.h>
#include <hip/hip_bf16.h>
#include <cstdint>
#include <cstddef>

typedef __bf16 bf16x8 __attribute__((ext_vector_type(8)));
typedef float f32x4 __attribute__((ext_vector_type(4)));
typedef unsigned short u16;

#define SEQ 2048
#define NH 16
#define HD 128
#define DMODEL 2048
#define NQKV 6144
#define NB 32     // seq blocks (2048/64)
#define KSEL 512  // top-k blocks per head

__device__ __forceinline__ u16 f2bf(float f) {
  unsigned u = __float_as_uint(f);
  u += 0x7fffu + ((u >> 16) & 1u);  // round-to-nearest-even
  return (u16)(u >> 16);
}
__device__ __forceinline__ float bf2f(u16 b) {
  return __uint_as_float(((unsigned)b) << 16);
}

// Async global->LDS, 16B per lane. LDS dest = wave-uniform base + lane*16.
__device__ __forceinline__ void async_copy16(const void* g, void* l) {
  __builtin_amdgcn_global_load_lds(
      (__attribute__((address_space(1))) void*)(unsigned long long)g,
      (__attribute__((address_space(3))) void*)(unsigned)(unsigned long long)l,
      16, 0, 0);
}

// ---------------- fused pre-pass: convert + 4x transpose + mask ----------------
// blocks 0..4095: hidden fp32->bf16; 4096..8191: weight transposes (1024 each);
// 8192..8207: per-head top-512 mask. All independent -> one launch.
__global__ __launch_bounds__(256) void pre_kernel(
    const float* __restrict__ hidden, const float* __restrict__ qw,
    const float* __restrict__ kw, const float* __restrict__ vw,
    const float* __restrict__ ow, const float* __restrict__ sp,
    u16* __restrict__ Xb, u16* __restrict__ Wqkvt, u16* __restrict__ Wot,
    int* __restrict__ sel_cnt, int* __restrict__ sel_idx, unsigned* __restrict__ sel_mask) {
  __shared__ __align__(16) char smem[64 * 65 * 4];
  int bid = blockIdx.x, t = threadIdx.x;
  if (bid < 4096) {  // convert: 2048x2048 fp32 -> bf16, float4 loads
    int i = bid * 256 + t;
    float4 v = ((const float4*)hidden)[i];
    ((ushort4*)Xb)[i] = make_ushort4(f2bf(v.x), f2bf(v.y), f2bf(v.z), f2bf(v.w));
    return;
  }
  if (bid < 8192) {  // transpose+convert one 64x64 tile of one weight
    int tb = bid - 4096;
    int wsel = tb >> 10, bx = tb & 31, by = (tb >> 5) & 31;
    const float* in = (wsel == 0) ? qw : (wsel == 1) ? kw : (wsel == 2) ? vw : ow;
    u16* out = (wsel == 3) ? Wot : Wqkvt + (size_t)wsel * DMODEL * 2048;
    float(*tile)[65] = (float(*)[65])smem;
    int c0 = bx * 64, r0 = by * 64;
    int c = t & 63, r4 = t >> 6;
    for (int i = 0; i < 16; ++i) {
      int r = r4 + i * 4;
      tile[r][c] = in[(size_t)(r0 + r) * 2048 + c0 + c];
    }
    __syncthreads();
    int rr = t & 63, c4 = t >> 6;
    for (int i = 0; i < 16; ++i) {
      int cc = c4 + i * 4;
      out[(size_t)(c0 + cc) * 2048 + r0 + rr] = f2bf(tile[rr][cc]);
    }
    return;
  }
  // mask: per-head top-512 by rank counting (256 threads, 4 vals each)
  int h = bid - 8192;
  float* vals = (float*)smem;
  unsigned char* selb = (unsigned char*)(smem + 4096);
  for (int i = 0; i < 4; ++i) vals[t + i * 256] = sp[h * 1024 + t + i * 256];
  __syncthreads();
  for (int i = 0; i < 4; ++i) {
    float v = vals[t + i * 256];
    int cnt = 0;
    for (int j = 0; j < 1024; ++j) cnt += vals[j] > v ? 1 : 0;
    selb[t + i * 256] = (cnt < (KSEL - 1)) ? 1 : 0;  // rank<511 <=> strictly > threshold
  }
  __syncthreads();
  if (t < NB) {
    int n = 0; unsigned m = 0;
    for (int kb = 0; kb < NB; ++kb) {
      if (selb[t * NB + kb]) { sel_idx[(h * NB + t) * NB + n] = kb; ++n; m |= 1u << kb; }
    }
    sel_cnt[h * NB + t] = n;
    sel_mask[h * NB + t] = m;
  }
}

// ---------------- bf16 GEMM: C[m][n] = sum_k A[m][k] * Bt[n][k] ----------------
// m97 structure: 128x128 tile, BK=64, global_load_lds width=16, XOR-swizzled LDS.
template <int WRITE_BF16>
__global__ __launch_bounds__(256, 2) void gemm_bt_kernel(
    const u16* __restrict__ A, const u16* __restrict__ Bt, void* __restrict__ Cout,
    int M, int N, int K) {
  __shared__ __align__(16) u16 As[8192];  // 128 rows x 64 elems, swizzled
  __shared__ __align__(16) u16 Bs[8192];
  const int t = threadIdx.x;
  const int lane = t & 63, w = t >> 6;
  const int wm = (w >> 1) * 64, wn = (w & 1) * 64;
  const int quad = lane >> 4, l16 = lane & 15;
  const int m0 = blockIdx.y * 128, n0 = blockIdx.x * 128;

  f32x4 acc[4][4] = {};

  for (int kt = 0; kt < K; kt += 64) {
    __syncthreads();  // previous iter's frag reads done before restaging
#pragma unroll
    for (int j = 0; j < 4; ++j) {
      int sl = w * 256 + j * 64 + lane;
      int row = sl >> 3, c = (sl & 7) ^ (row & 7);
      const u16* ga = A + (size_t)(m0 + row) * K + kt + c * 8;
      const u16* gb = Bt + (size_t)(n0 + row) * K + kt + c * 8;
      async_copy16(ga, &As[(size_t)(w * 256 + j * 64) * 8]);
      async_copy16(gb, &Bs[(size_t)(w * 256 + j * 64) * 8]);
    }
    __syncthreads();  // vmcnt(0) drain -> tile visible
#pragma unroll
    for (int ks = 0; ks < 2; ++ks) {
      bf16x8 af[4], bfr[4];
#pragma unroll
      for (int mt = 0; mt < 4; ++mt) {
        int row = wm + mt * 16 + l16;
        af[mt] = *(const bf16x8*)(&As[(row * 8 + ((ks * 4 + quad) ^ (l16 & 7))) * 8]);
      }
#pragma unroll
      for (int nt = 0; nt < 4; ++nt) {
        int row = wn + nt * 16 + l16;
        bfr[nt] = *(const bf16x8*)(&Bs[(row * 8 + ((ks * 4 + quad) ^ (l16 & 7))) * 8]);
      }
#pragma unroll
      for (int mt = 0; mt < 4; ++mt)
#pragma unroll
        for (int nt = 0; nt < 4; ++nt)
          acc[mt][nt] = __builtin_amdgcn_mfma_f32_16x16x32_bf16(af[mt], bfr[nt], acc[mt][nt], 0, 0, 0);
    }
  }
  // epilogue: C/D layout col=lane&15, row=quad*4+reg (m89-verified)
#pragma unroll
  for (int mt = 0; mt < 4; ++mt)
#pragma unroll
    for (int nt = 0; nt < 4; ++nt)
#pragma unroll
      for (int p = 0; p < 4; ++p) {
        int row = m0 + wm + mt * 16 + quad * 4 + p;
        int col = n0 + wn + nt * 16 + l16;
        if (WRITE_BF16)
          ((u16*)Cout)[(size_t)row * N + col] = f2bf(acc[mt][nt][p]);
        else
          ((float*)Cout)[(size_t)row * N + col] = acc[mt][nt][p];
      }
}

// ---------------- prep: RoPE on Q,K; V -> [h][d][s]; V block sums ----------------
__global__ __launch_bounds__(256, 2) void prep_kernel(
    const u16* __restrict__ QKVb, u16* __restrict__ Qh, u16* __restrict__ Kh,
    u16* __restrict__ Vt, float* __restrict__ Vbsum) {
  __shared__ float vtile[64][129];  // stride 129 words -> conflict-free column reads
  int sb = blockIdx.x, h = blockIdx.y;
  int s0 = sb * 64, t = threadIdx.x;
  int d = t & 127, rp = t >> 7;
  float inv_freq = powf(10000.0f, -(float)(2 * (d & 63)) / 128.0f);
  int dp = (d + 64) & 127;
  float sgn = (d < 64) ? -1.0f : 1.0f;
  for (int i = 0; i < 32; ++i) {
    int row = rp + i * 2;
    int s = s0 + row;
    const u16* base = QKVb + (size_t)s * NQKV + h * HD;
    float ang = (float)s * inv_freq;
    float cs = cosf(ang), sn = sinf(ang);
    float q = bf2f(base[d]), qp = bf2f(base[dp]);
    float k = bf2f(base[DMODEL + d]), kp = bf2f(base[DMODEL + dp]);
    Qh[((size_t)h * SEQ + s) * HD + d] = f2bf(q * cs + sgn * qp * sn);
    Kh[((size_t)h * SEQ + s) * HD + d] = f2bf(k * cs + sgn * kp * sn);
    vtile[row][d] = bf2f(base[2 * DMODEL + d]);
  }
  __syncthreads();
  int ss = t & 63, dg = t >> 6;
  for (int i = 0; i < 32; ++i) {
    int dd = dg + i * 4;
    Vt[((size_t)h * HD + dd) * SEQ + s0 + ss] = f2bf(vtile[ss][dd]);
  }
  if (t < HD) {
    float sum = 0.f;
    for (int r = 0; r < 64; ++r) sum += vtile[r][t];
    Vbsum[((size_t)h * NB + sb) * HD + t] = sum;
  }
}

// ---------------- block-sparse attention v3 ----------------
// Softmax-lite: fixed m=0 is EXACT (shift-invariance; scores ~N(0,0.8) so
// exp never overflows). l deferred to epilogue; no alpha rescale.
// Correction for exactly-zero masked scores: l += 64*(32-nsel), O += sum_unsel V.
// LDS = 16K(Ks) + 16K(Vs) + 8K(pbuf) = 40960 B exactly -> 4 blocks/CU,
// 4 waves/SIMD: stalls of one block hidden by 3 others (m114).
__global__ __launch_bounds__(256, 4) void attn_kernel(
    const u16* __restrict__ Qh, const u16* __restrict__ Kh, const u16* __restrict__ Vt,
    const float* __restrict__ Vbsum, const int* __restrict__ sel_cnt,
    const int* __restrict__ sel_idx, const unsigned* __restrict__ sel_mask,
    u16* __restrict__ attnb) {
  __shared__ __align__(16) u16 Ks[8192];       // 64 k-rows x 128 d (16 chunks), c^(r&15)
  __shared__ __align__(16) u16 Vs[8192];       // 128 d-rows x 64 s (8 chunks), c^(d&7)
  __shared__ __align__(16) u16 pbuf[4][1024];  // per-wave 16x64, chunk-swizzle c^(row&7)
  // XCD swizzle: 2 heads per XCD -> per-XCD K/V working set 2MB <= 4MB L2.
  int bid = blockIdx.x;
  int h = (bid & 7) * 2 + ((bid >> 3) >> 5);
  int qb = (bid >> 3) & 31;
  int t = threadIdx.x, lane = t & 63, w = t >> 6;
  int quad = lane >> 4, l16 = lane & 15;
  int rowblk = h * NB + qb;
  int nsel = sel_cnt[rowblk];
  unsigned smask = sel_mask[rowblk];
  const int* selrow = sel_idx + rowblk * NB;

  auto stageK = [&](int kb) {
    const u16* kbase = Kh + ((size_t)h * SEQ + kb * 64) * HD;
#pragma unroll
    for (int j = 0; j < 4; ++j) {
      int s = w * 256 + j * 64 + lane;
      int r = s >> 4, c = (s & 15) ^ (r & 15);
      async_copy16(kbase + (size_t)r * HD + c * 8, &Ks[(w * 256 + j * 64) * 8]);
    }
  };
  auto stageV = [&](int kb) {
    const u16* vbase = Vt + (size_t)h * HD * SEQ + kb * 64;
#pragma unroll
    for (int j = 0; j < 4; ++j) {
      int s = w * 256 + j * 64 + lane;
      int d = s >> 3, c = (s & 7) ^ (d & 7);
      async_copy16(vbase + (size_t)d * SEQ + c * 8, &Vs[(w * 256 + j * 64) * 8]);
    }
  };

  // vcorr in registers: sum of unselected V-block sums at this lane's 8 d-slots
  float vc[8] = {};
  for (int kb = 0; kb < NB; ++kb)
    if (!((smask >> kb) & 1u)) {
      const float* vb = Vbsum + ((size_t)h * NB + kb) * HD + l16;
#pragma unroll
      for (int nt = 0; nt < 8; ++nt) vc[nt] += vb[nt * 16];
    }
  // Q fragments: A-layout m=lane&15, k=quad*8+j (4 k-steps of 32)
  bf16x8 qf[4];
  {
    const u16* qbase = Qh + ((size_t)h * SEQ + qb * 64 + w * 16 + l16) * HD + quad * 8;
#pragma unroll
    for (int kk = 0; kk < 4; ++kk) qf[kk] = *(const bf16x8*)(qbase + kk * 32);
  }
  float rs[4] = {0.f, 0.f, 0.f, 0.f};  // lane-local sum of P (reduced in epilogue)
  f32x4 oacc[8] = {};
  const float scale = 0.08838834764831845f;  // 1/sqrt(128)
  u16* pb = pbuf[w];

  for (int si = 0; si < nsel; ++si) {
    int kb = selrow[si];
    __syncthreads();  // [C] prev iter's Ks/Vs reads done before restage
    stageK(kb);
    stageV(kb);
    __syncthreads();  // [A] vmcnt(0) drain per wave + all waves staged -> K,V ready

    f32x4 sacc[4] = {};
#pragma unroll
    for (int kk = 0; kk < 4; ++kk) {
#pragma unroll
      for (int nt = 0; nt < 4; ++nt) {
        int row = nt * 16 + l16;
        bf16x8 bfr = *(const bf16x8*)(&Ks[(row * 16 + ((kk * 4 + quad) ^ l16)) * 8]);
        sacc[nt] = __builtin_amdgcn_mfma_f32_16x16x32_bf16(qf[kk], bfr, sacc[nt], 0, 0, 0);
      }
    }
    // P = exp(s*scale), bf16-rounded; write C-layout -> pbuf rows, track row sums
#pragma unroll
    for (int nt = 0; nt < 4; ++nt) {
#pragma unroll
      for (int p = 0; p < 4; ++p) {
        float pv = __expf(sacc[nt][p] * scale);
        u16 pr = f2bf(pv);
        int row = quad * 4 + p, col = nt * 16 + l16;
        pb[row * 64 + (((col >> 3) ^ (row & 7)) << 3) + (col & 7)] = pr;
        rs[p] += bf2f(pr);  // l consistent with rounded P
      }
    }
    // same-wave LDS write->read fence (pbuf is wave-private; no cross-wave barrier)
    asm volatile("s_waitcnt lgkmcnt(0)" ::: "memory");
#pragma unroll
    for (int ks2 = 0; ks2 < 2; ++ks2) {
      bf16x8 pf = *(const bf16x8*)(pb + l16 * 64 + (((ks2 * 4 + quad) ^ (l16 & 7)) << 3));
#pragma unroll
      for (int nt = 0; nt < 8; ++nt) {
        int d = nt * 16 + l16;
        bf16x8 vf = *(const bf16x8*)(&Vs[(d * 8 + ((ks2 * 4 + quad) ^ (d & 7))) * 8]);
        oacc[nt] = __builtin_amdgcn_mfma_f32_16x16x32_bf16(pf, vf, oacc[nt], 0, 0, 0);
      }
    }
  }
  // epilogue: reduce rs over the 16 lanes of each quad-group (cols of the row)
#pragma unroll
  for (int p = 0; p < 4; ++p)
#pragma unroll
    for (int off = 1; off < 16; off <<= 1)
      rs[p] += __shfl_xor(rs[p], off, 64);
  float cntm = (float)(64 * (NB - nsel));  // masked cols contribute exp(0)=1 each
#pragma unroll
  for (int p = 0; p < 4; ++p) {
    float inv = 1.0f / (rs[p] + cntm);
    int row = qb * 64 + w * 16 + quad * 4 + p;
#pragma unroll
    for (int nt = 0; nt < 8; ++nt) {
      float o = (oacc[nt][p] + vc[nt]) * inv;
      attnb[(size_t)row * DMODEL + h * HD + nt * 16 + l16] = f2bf(o);
    }
  }
}

extern "C" void kernel_launch(void* const* d_in, const int* in_sizes, int n_in,
                              void* d_out, int out_size, void* d_ws, size_t ws_size,
                              hipStream_t stream) {
  const float* hidden = (const float*)d_in[0];
  const float* q_w = (const float*)d_in[1];
  const float* k_w = (const float*)d_in[2];
  const float* v_w = (const float*)d_in[3];
  const float* o_w = (const float*)d_in[4];
  const float* sp  = (const float*)d_in[5];

  char* ws = (char*)d_ws;
  size_t off = 0;
  auto alloc = [&](size_t bytes) -> void* {
    void* p = ws + off;
    off += (bytes + 255) & ~(size_t)255;
    return p;
  };
  u16* Xb     = (u16*)alloc((size_t)SEQ * DMODEL * 2);          // 8 MB (reused as attnb)
  u16* Wqkvt  = (u16*)alloc((size_t)NQKV * DMODEL * 2);         // 25 MB
  u16* Wot    = (u16*)alloc((size_t)DMODEL * DMODEL * 2);       // 8 MB
  u16* QKVb   = (u16*)alloc((size_t)SEQ * NQKV * 2);            // 25 MB
  u16* Qh     = (u16*)alloc((size_t)NH * SEQ * HD * 2);         // 8 MB
  u16* Kh     = (u16*)alloc((size_t)NH * SEQ * HD * 2);         // 8 MB
  u16* Vt     = (u16*)alloc((size_t)NH * HD * SEQ * 2);         // 8 MB
  float* Vbsum = (float*)alloc((size_t)NH * NB * HD * 4);       // 256 KB
  int* sel_cnt = (int*)alloc(NH * NB * 4);
  int* sel_idx = (int*)alloc(NH * NB * NB * 4);
  unsigned* sel_mask = (unsigned*)alloc(NH * NB * 4);
  u16* attnb = Xb;  // Xb dead after QKV GEMM; attnb written after -> safe alias

  pre_kernel<<<8208, 256, 0, stream>>>(hidden, q_w, k_w, v_w, o_w, sp,
                                       Xb, Wqkvt, Wot, sel_cnt, sel_idx, sel_mask);
  gemm_bt_kernel<1><<<dim3(NQKV / 128, SEQ / 128), 256, 0, stream>>>(
      Xb, Wqkvt, QKVb, SEQ, NQKV, DMODEL);
  prep_kernel<<<dim3(NB, NH), 256, 0, stream>>>(QKVb, Qh, Kh, Vt, Vbsum);
  attn_kernel<<<512, 256, 0, stream>>>(Qh, Kh, Vt, Vbsum, sel_cnt, sel_idx,
                                       sel_mask, attnb);
  gemm_bt_kernel<0><<<dim3(DMODEL / 128, SEQ / 128), 256, 0, stream>>>(
      attnb, Wot, d_out, SEQ, DMODEL, DMODEL);
}

// Round 4
// 297.048 us; speedup vs baseline: 1.1223x; 1.1223x over previous
//
#include <hip/hip_runtime.h>
#include <hip/hip_bf16.h>
#include <cstdint>
#include <cstddef>

typedef __bf16 bf16x8 __attribute__((ext_vector_type(8)));
typedef float f32x4 __attribute__((ext_vector_type(4)));
typedef unsigned short u16;

#define SEQ 2048
#define NH 16
#define HD 128
#define DMODEL 2048
#define NQKV 6144
#define NB 32     // seq blocks (2048/64)
#define KSEL 512  // top-k blocks per head

__device__ __forceinline__ u16 f2bf(float f) {
  unsigned u = __float_as_uint(f);
  u += 0x7fffu + ((u >> 16) & 1u);  // round-to-nearest-even
  return (u16)(u >> 16);
}
__device__ __forceinline__ float bf2f(u16 b) {
  return __uint_as_float(((unsigned)b) << 16);
}

// Async global->LDS, 16B per lane. LDS dest = wave-uniform base + lane*16.
__device__ __forceinline__ void async_copy16(const void* g, void* l) {
  __builtin_amdgcn_global_load_lds(
      (__attribute__((address_space(1))) void*)(unsigned long long)g,
      (__attribute__((address_space(3))) void*)(unsigned)(unsigned long long)l,
      16, 0, 0);
}

// ---------------- fused pre-pass: convert + 4x transpose + mask ----------------
__global__ __launch_bounds__(256) void pre_kernel(
    const float* __restrict__ hidden, const float* __restrict__ qw,
    const float* __restrict__ kw, const float* __restrict__ vw,
    const float* __restrict__ ow, const float* __restrict__ sp,
    u16* __restrict__ Xb, u16* __restrict__ Wqkvt, u16* __restrict__ Wot,
    int* __restrict__ sel_cnt, int* __restrict__ sel_idx, unsigned* __restrict__ sel_mask) {
  __shared__ __align__(16) char smem[64 * 65 * 4];
  int bid = blockIdx.x, t = threadIdx.x;
  if (bid < 4096) {  // convert: 2048x2048 fp32 -> bf16, float4 loads
    int i = bid * 256 + t;
    float4 v = ((const float4*)hidden)[i];
    ((ushort4*)Xb)[i] = make_ushort4(f2bf(v.x), f2bf(v.y), f2bf(v.z), f2bf(v.w));
    return;
  }
  if (bid < 8192) {  // transpose+convert one 64x64 tile of one weight
    int tb = bid - 4096;
    int wsel = tb >> 10, bx = tb & 31, by = (tb >> 5) & 31;
    const float* in = (wsel == 0) ? qw : (wsel == 1) ? kw : (wsel == 2) ? vw : ow;
    u16* out = (wsel == 3) ? Wot : Wqkvt + (size_t)wsel * DMODEL * 2048;
    float(*tile)[65] = (float(*)[65])smem;
    int c0 = bx * 64, r0 = by * 64;
    int c = t & 63, r4 = t >> 6;
    for (int i = 0; i < 16; ++i) {
      int r = r4 + i * 4;
      tile[r][c] = in[(size_t)(r0 + r) * 2048 + c0 + c];
    }
    __syncthreads();
    int rr = t & 63, c4 = t >> 6;
    for (int i = 0; i < 16; ++i) {
      int cc = c4 + i * 4;
      out[(size_t)(c0 + cc) * 2048 + r0 + rr] = f2bf(tile[rr][cc]);
    }
    return;
  }
  // mask: per-head top-512 by rank counting (256 threads, 4 vals each)
  int h = bid - 8192;
  float* vals = (float*)smem;
  unsigned char* selb = (unsigned char*)(smem + 4096);
  for (int i = 0; i < 4; ++i) vals[t + i * 256] = sp[h * 1024 + t + i * 256];
  __syncthreads();
  for (int i = 0; i < 4; ++i) {
    float v = vals[t + i * 256];
    int cnt = 0;
    for (int j = 0; j < 1024; ++j) cnt += vals[j] > v ? 1 : 0;
    selb[t + i * 256] = (cnt < (KSEL - 1)) ? 1 : 0;  // rank<511 <=> strictly > threshold
  }
  __syncthreads();
  if (t < NB) {
    int n = 0; unsigned m = 0;
    for (int kb = 0; kb < NB; ++kb) {
      if (selb[t * NB + kb]) { sel_idx[(h * NB + t) * NB + n] = kb; ++n; m |= 1u << kb; }
    }
    sel_cnt[h * NB + t] = n;
    sel_mask[h * NB + t] = m;
  }
}

// ---------------- bf16 GEMM: C[m][n] = sum_k A[m][k] * Bt[n][k] ----------------
// m97 structure: 128x128 tile, BK=64, global_load_lds width=16, XOR-swizzled LDS.
template <int WRITE_BF16>
__global__ __launch_bounds__(256, 2) void gemm_bt_kernel(
    const u16* __restrict__ A, const u16* __restrict__ Bt, void* __restrict__ Cout,
    int M, int N, int K) {
  __shared__ __align__(16) u16 As[8192];  // 128 rows x 64 elems, swizzled
  __shared__ __align__(16) u16 Bs[8192];
  const int t = threadIdx.x;
  const int lane = t & 63, w = t >> 6;
  const int wm = (w >> 1) * 64, wn = (w & 1) * 64;
  const int quad = lane >> 4, l16 = lane & 15;
  const int m0 = blockIdx.y * 128, n0 = blockIdx.x * 128;

  f32x4 acc[4][4] = {};

  for (int kt = 0; kt < K; kt += 64) {
    __syncthreads();  // previous iter's frag reads done before restaging
#pragma unroll
    for (int j = 0; j < 4; ++j) {
      int sl = w * 256 + j * 64 + lane;
      int row = sl >> 3, c = (sl & 7) ^ (row & 7);
      const u16* ga = A + (size_t)(m0 + row) * K + kt + c * 8;
      const u16* gb = Bt + (size_t)(n0 + row) * K + kt + c * 8;
      async_copy16(ga, &As[(size_t)(w * 256 + j * 64) * 8]);
      async_copy16(gb, &Bs[(size_t)(w * 256 + j * 64) * 8]);
    }
    __syncthreads();  // vmcnt(0) drain -> tile visible
#pragma unroll
    for (int ks = 0; ks < 2; ++ks) {
      bf16x8 af[4], bfr[4];
#pragma unroll
      for (int mt = 0; mt < 4; ++mt) {
        int row = wm + mt * 16 + l16;
        af[mt] = *(const bf16x8*)(&As[(row * 8 + ((ks * 4 + quad) ^ (l16 & 7))) * 8]);
      }
#pragma unroll
      for (int nt = 0; nt < 4; ++nt) {
        int row = wn + nt * 16 + l16;
        bfr[nt] = *(const bf16x8*)(&Bs[(row * 8 + ((ks * 4 + quad) ^ (l16 & 7))) * 8]);
      }
#pragma unroll
      for (int mt = 0; mt < 4; ++mt)
#pragma unroll
        for (int nt = 0; nt < 4; ++nt)
          acc[mt][nt] = __builtin_amdgcn_mfma_f32_16x16x32_bf16(af[mt], bfr[nt], acc[mt][nt], 0, 0, 0);
    }
  }
  // epilogue: C/D layout col=lane&15, row=quad*4+reg (m89-verified)
#pragma unroll
  for (int mt = 0; mt < 4; ++mt)
#pragma unroll
    for (int nt = 0; nt < 4; ++nt)
#pragma unroll
      for (int p = 0; p < 4; ++p) {
        int row = m0 + wm + mt * 16 + quad * 4 + p;
        int col = n0 + wn + nt * 16 + l16;
        if (WRITE_BF16)
          ((u16*)Cout)[(size_t)row * N + col] = f2bf(acc[mt][nt][p]);
        else
          ((float*)Cout)[(size_t)row * N + col] = acc[mt][nt][p];
      }
}

// ---------------- prep: RoPE on Q,K; V -> [h][d][s]; V block sums ----------------
__global__ __launch_bounds__(256, 2) void prep_kernel(
    const u16* __restrict__ QKVb, u16* __restrict__ Qh, u16* __restrict__ Kh,
    u16* __restrict__ Vt, float* __restrict__ Vbsum) {
  __shared__ float vtile[64][129];  // stride 129 words -> conflict-free column reads
  int sb = blockIdx.x, h = blockIdx.y;
  int s0 = sb * 64, t = threadIdx.x;
  int d = t & 127, rp = t >> 7;
  float inv_freq = powf(10000.0f, -(float)(2 * (d & 63)) / 128.0f);
  int dp = (d + 64) & 127;
  float sgn = (d < 64) ? -1.0f : 1.0f;
  for (int i = 0; i < 32; ++i) {
    int row = rp + i * 2;
    int s = s0 + row;
    const u16* base = QKVb + (size_t)s * NQKV + h * HD;
    float ang = (float)s * inv_freq;
    float cs = cosf(ang), sn = sinf(ang);
    float q = bf2f(base[d]), qp = bf2f(base[dp]);
    float k = bf2f(base[DMODEL + d]), kp = bf2f(base[DMODEL + dp]);
    Qh[((size_t)h * SEQ + s) * HD + d] = f2bf(q * cs + sgn * qp * sn);
    Kh[((size_t)h * SEQ + s) * HD + d] = f2bf(k * cs + sgn * kp * sn);
    vtile[row][d] = bf2f(base[2 * DMODEL + d]);
  }
  __syncthreads();
  int ss = t & 63, dg = t >> 6;
  for (int i = 0; i < 32; ++i) {
    int dd = dg + i * 4;
    Vt[((size_t)h * HD + dd) * SEQ + s0 + ss] = f2bf(vtile[ss][dd]);
  }
  if (t < HD) {
    float sum = 0.f;
    for (int r = 0; r < 64; ++r) sum += vtile[r][t];
    Vbsum[((size_t)h * NB + sb) * HD + t] = sum;
  }
}

// ---------------- block-sparse attention v4: full software pipeline ----------------
// Softmax-lite (m=0 fixed, exact); masked-zero correction in epilogue.
// K AND V double-buffered, ONE barrier per iteration: staging for iter i+1
// is issued at the top of iter i and only drained at the end-of-iter barrier
// -> a full iteration (~1000 cyc) of load cover. Buffer safety: end-of-iter-i
// barrier orders all reads of buf(i) before iter-(i+1) stages buf(i+2)=buf(i).
// LDS = 2*16K + 2*16K + 8K = 72 KB -> 2 WGs/CU = full co-residency of 512 WGs.
__global__ __launch_bounds__(256, 2) void attn_kernel(
    const u16* __restrict__ Qh, const u16* __restrict__ Kh, const u16* __restrict__ Vt,
    const float* __restrict__ Vbsum, const int* __restrict__ sel_cnt,
    const int* __restrict__ sel_idx, const unsigned* __restrict__ sel_mask,
    u16* __restrict__ attnb) {
  __shared__ __align__(16) u16 Ks[2][8192];    // 64 k-rows x 128 d (16 chunks), c^(r&15)
  __shared__ __align__(16) u16 Vs[2][8192];    // 128 d-rows x 64 s (8 chunks), c^(d&7)
  __shared__ __align__(16) u16 pbuf[4][1024];  // per-wave 16x64, chunk-swizzle c^(row&7)
  // XCD swizzle: 2 heads per XCD -> per-XCD K/V working set 2MB <= 4MB L2.
  int bid = blockIdx.x;
  int h = (bid & 7) * 2 + ((bid >> 3) >> 5);
  int qb = (bid >> 3) & 31;
  int t = threadIdx.x, lane = t & 63, w = t >> 6;
  int quad = lane >> 4, l16 = lane & 15;
  int rowblk = h * NB + qb;
  int nsel = sel_cnt[rowblk];
  unsigned smask = sel_mask[rowblk];
  const int* selrow = sel_idx + rowblk * NB;

  auto stageK = [&](int buf, int kb) {
    const u16* kbase = Kh + ((size_t)h * SEQ + kb * 64) * HD;
#pragma unroll
    for (int j = 0; j < 4; ++j) {
      int s = w * 256 + j * 64 + lane;
      int r = s >> 4, c = (s & 15) ^ (r & 15);
      async_copy16(kbase + (size_t)r * HD + c * 8, &Ks[buf][(w * 256 + j * 64) * 8]);
    }
  };
  auto stageV = [&](int buf, int kb) {
    const u16* vbase = Vt + (size_t)h * HD * SEQ + kb * 64;
#pragma unroll
    for (int j = 0; j < 4; ++j) {
      int s = w * 256 + j * 64 + lane;
      int d = s >> 3, c = (s & 7) ^ (d & 7);
      async_copy16(vbase + (size_t)d * SEQ + c * 8, &Vs[buf][(w * 256 + j * 64) * 8]);
    }
  };

  if (nsel > 0) { stageK(0, selrow[0]); stageV(0, selrow[0]); }

  // vcorr in registers: sum of unselected V-block sums at this lane's 8 d-slots
  float vc[8] = {};
  for (int kb = 0; kb < NB; ++kb)
    if (!((smask >> kb) & 1u)) {
      const float* vb = Vbsum + ((size_t)h * NB + kb) * HD + l16;
#pragma unroll
      for (int nt = 0; nt < 8; ++nt) vc[nt] += vb[nt * 16];
    }
  // Q fragments: A-layout m=lane&15, k=quad*8+j (4 k-steps of 32)
  bf16x8 qf[4];
  {
    const u16* qbase = Qh + ((size_t)h * SEQ + qb * 64 + w * 16 + l16) * HD + quad * 8;
#pragma unroll
    for (int kk = 0; kk < 4; ++kk) qf[kk] = *(const bf16x8*)(qbase + kk * 32);
  }
  float rs[4] = {0.f, 0.f, 0.f, 0.f};  // lane-local sum of P (reduced in epilogue)
  f32x4 oacc[8] = {};
  const float scale = 0.08838834764831845f;  // 1/sqrt(128)
  u16* pb = pbuf[w];

  __syncthreads();  // drain prologue staging of buf0

  for (int si = 0; si < nsel; ++si) {
    int cur = si & 1;
    if (si + 1 < nsel) {  // prefetch next K AND V; drained at end-of-iter barrier
      stageK(1 - cur, selrow[si + 1]);
      stageV(1 - cur, selrow[si + 1]);
    }

    f32x4 sacc[4] = {};
#pragma unroll
    for (int kk = 0; kk < 4; ++kk) {
#pragma unroll
      for (int nt = 0; nt < 4; ++nt) {
        int row = nt * 16 + l16;
        bf16x8 bfr = *(const bf16x8*)(&Ks[cur][(row * 16 + ((kk * 4 + quad) ^ l16)) * 8]);
        sacc[nt] = __builtin_amdgcn_mfma_f32_16x16x32_bf16(qf[kk], bfr, sacc[nt], 0, 0, 0);
      }
    }
    // P = exp(s*scale), bf16-rounded; C-layout -> pbuf rows; track row sums
#pragma unroll
    for (int nt = 0; nt < 4; ++nt) {
#pragma unroll
      for (int p = 0; p < 4; ++p) {
        float pv = __expf(sacc[nt][p] * scale);
        u16 pr = f2bf(pv);
        int row = quad * 4 + p, col = nt * 16 + l16;
        pb[row * 64 + (((col >> 3) ^ (row & 7)) << 3) + (col & 7)] = pr;
        rs[p] += bf2f(pr);  // l consistent with rounded P
      }
    }
    // same-wave LDS write->read fence (pbuf wave-private; no cross-wave barrier)
    asm volatile("s_waitcnt lgkmcnt(0)" ::: "memory");
#pragma unroll
    for (int ks2 = 0; ks2 < 2; ++ks2) {
      bf16x8 pf = *(const bf16x8*)(pb + l16 * 64 + (((ks2 * 4 + quad) ^ (l16 & 7)) << 3));
#pragma unroll
      for (int nt = 0; nt < 8; ++nt) {
        int d = nt * 16 + l16;
        bf16x8 vf = *(const bf16x8*)(&Vs[cur][(d * 8 + ((ks2 * 4 + quad) ^ (d & 7))) * 8]);
        oacc[nt] = __builtin_amdgcn_mfma_f32_16x16x32_bf16(pf, vf, oacc[nt], 0, 0, 0);
      }
    }
    __syncthreads();  // single barrier/iter: drains next-buf staging (issued a
                      // full iter ago) + orders buf(cur) reads before reuse
  }
  // epilogue: reduce rs over the 16 lanes of each quad-group
#pragma unroll
  for (int p = 0; p < 4; ++p)
#pragma unroll
    for (int off = 1; off < 16; off <<= 1)
      rs[p] += __shfl_xor(rs[p], off, 64);
  float cntm = (float)(64 * (NB - nsel));  // masked cols contribute exp(0)=1 each
#pragma unroll
  for (int p = 0; p < 4; ++p) {
    float inv = 1.0f / (rs[p] + cntm);
    int row = qb * 64 + w * 16 + quad * 4 + p;
#pragma unroll
    for (int nt = 0; nt < 8; ++nt) {
      float o = (oacc[nt][p] + vc[nt]) * inv;
      attnb[(size_t)row * DMODEL + h * HD + nt * 16 + l16] = f2bf(o);
    }
  }
}

extern "C" void kernel_launch(void* const* d_in, const int* in_sizes, int n_in,
                              void* d_out, int out_size, void* d_ws, size_t ws_size,
                              hipStream_t stream) {
  const float* hidden = (const float*)d_in[0];
  const float* q_w = (const float*)d_in[1];
  const float* k_w = (const float*)d_in[2];
  const float* v_w = (const float*)d_in[3];
  const float* o_w = (const float*)d_in[4];
  const float* sp  = (const float*)d_in[5];

  char* ws = (char*)d_ws;
  size_t off = 0;
  auto alloc = [&](size_t bytes) -> void* {
    void* p = ws + off;
    off += (bytes + 255) & ~(size_t)255;
    return p;
  };
  u16* Xb     = (u16*)alloc((size_t)SEQ * DMODEL * 2);          // 8 MB (reused as attnb)
  u16* Wqkvt  = (u16*)alloc((size_t)NQKV * DMODEL * 2);         // 25 MB
  u16* Wot    = (u16*)alloc((size_t)DMODEL * DMODEL * 2);       // 8 MB
  u16* QKVb   = (u16*)alloc((size_t)SEQ * NQKV * 2);            // 25 MB
  u16* Qh     = (u16*)alloc((size_t)NH * SEQ * HD * 2);         // 8 MB
  u16* Kh     = (u16*)alloc((size_t)NH * SEQ * HD * 2);         // 8 MB
  u16* Vt     = (u16*)alloc((size_t)NH * HD * SEQ * 2);         // 8 MB
  float* Vbsum = (float*)alloc((size_t)NH * NB * HD * 4);       // 256 KB
  int* sel_cnt = (int*)alloc(NH * NB * 4);
  int* sel_idx = (int*)alloc(NH * NB * NB * 4);
  unsigned* sel_mask = (unsigned*)alloc(NH * NB * 4);
  u16* attnb = Xb;  // Xb dead after QKV GEMM; attnb written after -> safe alias

  pre_kernel<<<8208, 256, 0, stream>>>(hidden, q_w, k_w, v_w, o_w, sp,
                                       Xb, Wqkvt, Wot, sel_cnt, sel_idx, sel_mask);
  gemm_bt_kernel<1><<<dim3(NQKV / 128, SEQ / 128), 256, 0, stream>>>(
      Xb, Wqkvt, QKVb, SEQ, NQKV, DMODEL);
  prep_kernel<<<dim3(NB, NH), 256, 0, stream>>>(QKVb, Qh, Kh, Vt, Vbsum);
  attn_kernel<<<512, 256, 0, stream>>>(Qh, Kh, Vt, Vbsum, sel_cnt, sel_idx,
                                       sel_mask, attnb);
  gemm_bt_kernel<0><<<dim3(DMODEL / 128, SEQ / 128), 256, 0, stream>>>(
      attnb, Wot, d_out, SEQ, DMODEL, DMODEL);
}

// Round 5
// 289.442 us; speedup vs baseline: 1.1518x; 1.0263x over previous
//
#include <hip/hip_runtime.h>
#include <hip/hip_bf16.h>
#include <cstdint>
#include <cstddef>

typedef __bf16 bf16x8 __attribute__((ext_vector_type(8)));
typedef float f32x4 __attribute__((ext_vector_type(4)));
typedef unsigned short u16;

#define SEQ 2048
#define NH 16
#define HD 128
#define DMODEL 2048
#define NQKV 6144
#define NB 32     // seq blocks (2048/64)
#define KSEL 512  // top-k blocks per head

__device__ __forceinline__ u16 f2bf(float f) {
  unsigned u = __float_as_uint(f);
  u += 0x7fffu + ((u >> 16) & 1u);  // round-to-nearest-even
  return (u16)(u >> 16);
}
__device__ __forceinline__ float bf2f(u16 b) {
  return __uint_as_float(((unsigned)b) << 16);
}

// Async global->LDS, 16B per lane. LDS dest = wave-uniform base + lane*16.
__device__ __forceinline__ void async_copy16(const void* g, void* l) {
  __builtin_amdgcn_global_load_lds(
      (__attribute__((address_space(1))) void*)(unsigned long long)g,
      (__attribute__((address_space(3))) void*)(unsigned)(unsigned long long)l,
      16, 0, 0);
}

// ---------------- fused pre-pass v2 ----------------
// bid 0..15: mask (serial rank-count, ~7us -> dispatched FIRST to hide in BW work)
// bid 16..1039: convert (1024 blocks, 4 float4/thread -> 4x MLP, 8x fewer blocks)
// bid 1040..3087: transposes (2048 blocks x 2 tiles; ushort4 writes = 8B/lane)
__global__ __launch_bounds__(256) void pre_kernel(
    const float* __restrict__ hidden, const float* __restrict__ qw,
    const float* __restrict__ kw, const float* __restrict__ vw,
    const float* __restrict__ ow, const float* __restrict__ sp,
    u16* __restrict__ Xb, u16* __restrict__ Wqkvt, u16* __restrict__ Wot,
    int* __restrict__ sel_cnt, int* __restrict__ sel_idx, unsigned* __restrict__ sel_mask) {
  __shared__ __align__(16) char smem[64 * 65 * 4];
  int bid = blockIdx.x, t = threadIdx.x;
  if (bid < 16) {  // mask: per-head top-512 by rank counting
    int h = bid;
    float* vals = (float*)smem;
    unsigned char* selb = (unsigned char*)(smem + 4096);
    for (int i = 0; i < 4; ++i) vals[t + i * 256] = sp[h * 1024 + t + i * 256];
    __syncthreads();
    for (int i = 0; i < 4; ++i) {
      float v = vals[t + i * 256];
      int cnt = 0;
      for (int j = 0; j < 1024; ++j) cnt += vals[j] > v ? 1 : 0;
      selb[t + i * 256] = (cnt < (KSEL - 1)) ? 1 : 0;  // rank<511 <=> strictly > thresh
    }
    __syncthreads();
    if (t < NB) {
      int n = 0; unsigned m = 0;
      for (int kb = 0; kb < NB; ++kb) {
        if (selb[t * NB + kb]) { sel_idx[(h * NB + t) * NB + n] = kb; ++n; m |= 1u << kb; }
      }
      sel_cnt[h * NB + t] = n;
      sel_mask[h * NB + t] = m;
    }
    return;
  }
  if (bid < 1040) {  // convert: 2048x2048 fp32 -> bf16, 4 independent float4/thread
    int base = (bid - 16) * 1024 + t;
    float4 v0 = ((const float4*)hidden)[base];
    float4 v1 = ((const float4*)hidden)[base + 256];
    float4 v2 = ((const float4*)hidden)[base + 512];
    float4 v3 = ((const float4*)hidden)[base + 768];
    ((ushort4*)Xb)[base]       = make_ushort4(f2bf(v0.x), f2bf(v0.y), f2bf(v0.z), f2bf(v0.w));
    ((ushort4*)Xb)[base + 256] = make_ushort4(f2bf(v1.x), f2bf(v1.y), f2bf(v1.z), f2bf(v1.w));
    ((ushort4*)Xb)[base + 512] = make_ushort4(f2bf(v2.x), f2bf(v2.y), f2bf(v2.z), f2bf(v2.w));
    ((ushort4*)Xb)[base + 768] = make_ushort4(f2bf(v3.x), f2bf(v3.y), f2bf(v3.z), f2bf(v3.w));
    return;
  }
  // transpose+convert: 2 64x64 tiles per block
  float(*tile)[65] = (float(*)[65])smem;  // pad 65: both phases <=2-way bank alias
  for (int ti = 0; ti < 2; ++ti) {
    int tidx = (bid - 1040) * 2 + ti;  // 0..4095
    int wsel = tidx >> 10, rem = tidx & 1023, bx = rem & 31, by = rem >> 5;
    const float* in = (wsel == 0) ? qw : (wsel == 1) ? kw : (wsel == 2) ? vw : ow;
    u16* out = (wsel == 3) ? Wot : Wqkvt + (size_t)wsel * DMODEL * 2048;
    int c0 = bx * 64, r0 = by * 64;
    if (ti) __syncthreads();  // tile reuse fence
#pragma unroll
    for (int i = 0; i < 4; ++i) {  // read: float4-coalesced (256B/row/16 lanes)
      int chunk = i * 256 + t, r = chunk >> 4, c4 = chunk & 15;
      float4 v = *(const float4*)(in + (size_t)(r0 + r) * 2048 + c0 + c4 * 4);
      tile[r][c4 * 4 + 0] = v.x; tile[r][c4 * 4 + 1] = v.y;
      tile[r][c4 * 4 + 2] = v.z; tile[r][c4 * 4 + 3] = v.w;
    }
    __syncthreads();
#pragma unroll
    for (int i = 0; i < 4; ++i) {  // write: ushort4-coalesced (128B/16 lanes)
      int item = i * 256 + t, cc = item >> 4, rr4 = item & 15;
      ushort4 o = make_ushort4(f2bf(tile[rr4 * 4 + 0][cc]), f2bf(tile[rr4 * 4 + 1][cc]),
                               f2bf(tile[rr4 * 4 + 2][cc]), f2bf(tile[rr4 * 4 + 3][cc]));
      *(ushort4*)(out + (size_t)(c0 + cc) * 2048 + r0 + rr4 * 4) = o;
    }
  }
}

// ---------------- bf16 GEMM: C[m][n] = sum_k A[m][k] * Bt[n][k] ----------------
// m97 structure: 128x128 tile, BK=64, global_load_lds width=16, XOR-swizzled LDS.
template <int WRITE_BF16>
__global__ __launch_bounds__(256, 2) void gemm_bt_kernel(
    const u16* __restrict__ A, const u16* __restrict__ Bt, void* __restrict__ Cout,
    int M, int N, int K) {
  __shared__ __align__(16) u16 As[8192];  // 128 rows x 64 elems, swizzled
  __shared__ __align__(16) u16 Bs[8192];
  const int t = threadIdx.x;
  const int lane = t & 63, w = t >> 6;
  const int wm = (w >> 1) * 64, wn = (w & 1) * 64;
  const int quad = lane >> 4, l16 = lane & 15;
  const int m0 = blockIdx.y * 128, n0 = blockIdx.x * 128;

  f32x4 acc[4][4] = {};

  for (int kt = 0; kt < K; kt += 64) {
    __syncthreads();  // previous iter's frag reads done before restaging
#pragma unroll
    for (int j = 0; j < 4; ++j) {
      int sl = w * 256 + j * 64 + lane;
      int row = sl >> 3, c = (sl & 7) ^ (row & 7);
      const u16* ga = A + (size_t)(m0 + row) * K + kt + c * 8;
      const u16* gb = Bt + (size_t)(n0 + row) * K + kt + c * 8;
      async_copy16(ga, &As[(size_t)(w * 256 + j * 64) * 8]);
      async_copy16(gb, &Bs[(size_t)(w * 256 + j * 64) * 8]);
    }
    __syncthreads();  // vmcnt(0) drain -> tile visible
#pragma unroll
    for (int ks = 0; ks < 2; ++ks) {
      bf16x8 af[4], bfr[4];
#pragma unroll
      for (int mt = 0; mt < 4; ++mt) {
        int row = wm + mt * 16 + l16;
        af[mt] = *(const bf16x8*)(&As[(row * 8 + ((ks * 4 + quad) ^ (l16 & 7))) * 8]);
      }
#pragma unroll
      for (int nt = 0; nt < 4; ++nt) {
        int row = wn + nt * 16 + l16;
        bfr[nt] = *(const bf16x8*)(&Bs[(row * 8 + ((ks * 4 + quad) ^ (l16 & 7))) * 8]);
      }
#pragma unroll
      for (int mt = 0; mt < 4; ++mt)
#pragma unroll
        for (int nt = 0; nt < 4; ++nt)
          acc[mt][nt] = __builtin_amdgcn_mfma_f32_16x16x32_bf16(af[mt], bfr[nt], acc[mt][nt], 0, 0, 0);
    }
  }
  // epilogue: C/D layout col=lane&15, row=quad*4+reg (m89-verified)
#pragma unroll
  for (int mt = 0; mt < 4; ++mt)
#pragma unroll
    for (int nt = 0; nt < 4; ++nt)
#pragma unroll
      for (int p = 0; p < 4; ++p) {
        int row = m0 + wm + mt * 16 + quad * 4 + p;
        int col = n0 + wn + nt * 16 + l16;
        if (WRITE_BF16)
          ((u16*)Cout)[(size_t)row * N + col] = f2bf(acc[mt][nt][p]);
        else
          ((float*)Cout)[(size_t)row * N + col] = acc[mt][nt][p];
      }
}

// ---------------- prep: RoPE on Q,K; V -> [h][d][s]; V block sums ----------------
__global__ __launch_bounds__(256, 2) void prep_kernel(
    const u16* __restrict__ QKVb, u16* __restrict__ Qh, u16* __restrict__ Kh,
    u16* __restrict__ Vt, float* __restrict__ Vbsum) {
  __shared__ float vtile[64][129];  // stride 129 words -> conflict-free column reads
  int sb = blockIdx.x, h = blockIdx.y;
  int s0 = sb * 64, t = threadIdx.x;
  int d = t & 127, rp = t >> 7;
  float inv_freq = powf(10000.0f, -(float)(2 * (d & 63)) / 128.0f);
  int dp = (d + 64) & 127;
  float sgn = (d < 64) ? -1.0f : 1.0f;
  for (int i = 0; i < 32; ++i) {
    int row = rp + i * 2;
    int s = s0 + row;
    const u16* base = QKVb + (size_t)s * NQKV + h * HD;
    float ang = (float)s * inv_freq;
    float cs = cosf(ang), sn = sinf(ang);
    float q = bf2f(base[d]), qp = bf2f(base[dp]);
    float k = bf2f(base[DMODEL + d]), kp = bf2f(base[DMODEL + dp]);
    Qh[((size_t)h * SEQ + s) * HD + d] = f2bf(q * cs + sgn * qp * sn);
    Kh[((size_t)h * SEQ + s) * HD + d] = f2bf(k * cs + sgn * kp * sn);
    vtile[row][d] = bf2f(base[2 * DMODEL + d]);
  }
  __syncthreads();
  int ss = t & 63, dg = t >> 6;
  for (int i = 0; i < 32; ++i) {
    int dd = dg + i * 4;
    Vt[((size_t)h * HD + dd) * SEQ + s0 + ss] = f2bf(vtile[ss][dd]);
  }
  if (t < HD) {
    float sum = 0.f;
    for (int r = 0; r < 64; ++r) sum += vtile[r][t];
    Vbsum[((size_t)h * NB + sb) * HD + t] = sum;
  }
}

// ---------------- block-sparse attention v4: full software pipeline ----------------
// Softmax-lite (m=0 fixed, exact); masked-zero correction in epilogue.
// K AND V double-buffered, ONE barrier per iteration.
// LDS = 2*16K + 2*16K + 8K = 72 KB -> 2 WGs/CU = full co-residency of 512 WGs.
__global__ __launch_bounds__(256, 2) void attn_kernel(
    const u16* __restrict__ Qh, const u16* __restrict__ Kh, const u16* __restrict__ Vt,
    const float* __restrict__ Vbsum, const int* __restrict__ sel_cnt,
    const int* __restrict__ sel_idx, const unsigned* __restrict__ sel_mask,
    u16* __restrict__ attnb) {
  __shared__ __align__(16) u16 Ks[2][8192];    // 64 k-rows x 128 d (16 chunks), c^(r&15)
  __shared__ __align__(16) u16 Vs[2][8192];    // 128 d-rows x 64 s (8 chunks), c^(d&7)
  __shared__ __align__(16) u16 pbuf[4][1024];  // per-wave 16x64, chunk-swizzle c^(row&7)
  // XCD swizzle: 2 heads per XCD -> per-XCD K/V working set 2MB <= 4MB L2.
  int bid = blockIdx.x;
  int h = (bid & 7) * 2 + ((bid >> 3) >> 5);
  int qb = (bid >> 3) & 31;
  int t = threadIdx.x, lane = t & 63, w = t >> 6;
  int quad = lane >> 4, l16 = lane & 15;
  int rowblk = h * NB + qb;
  int nsel = sel_cnt[rowblk];
  unsigned smask = sel_mask[rowblk];
  const int* selrow = sel_idx + rowblk * NB;

  auto stageK = [&](int buf, int kb) {
    const u16* kbase = Kh + ((size_t)h * SEQ + kb * 64) * HD;
#pragma unroll
    for (int j = 0; j < 4; ++j) {
      int s = w * 256 + j * 64 + lane;
      int r = s >> 4, c = (s & 15) ^ (r & 15);
      async_copy16(kbase + (size_t)r * HD + c * 8, &Ks[buf][(w * 256 + j * 64) * 8]);
    }
  };
  auto stageV = [&](int buf, int kb) {
    const u16* vbase = Vt + (size_t)h * HD * SEQ + kb * 64;
#pragma unroll
    for (int j = 0; j < 4; ++j) {
      int s = w * 256 + j * 64 + lane;
      int d = s >> 3, c = (s & 7) ^ (d & 7);
      async_copy16(vbase + (size_t)d * SEQ + c * 8, &Vs[buf][(w * 256 + j * 64) * 8]);
    }
  };

  if (nsel > 0) { stageK(0, selrow[0]); stageV(0, selrow[0]); }

  // vcorr in registers: sum of unselected V-block sums at this lane's 8 d-slots
  float vc[8] = {};
  for (int kb = 0; kb < NB; ++kb)
    if (!((smask >> kb) & 1u)) {
      const float* vb = Vbsum + ((size_t)h * NB + kb) * HD + l16;
#pragma unroll
      for (int nt = 0; nt < 8; ++nt) vc[nt] += vb[nt * 16];
    }
  // Q fragments: A-layout m=lane&15, k=quad*8+j (4 k-steps of 32)
  bf16x8 qf[4];
  {
    const u16* qbase = Qh + ((size_t)h * SEQ + qb * 64 + w * 16 + l16) * HD + quad * 8;
#pragma unroll
    for (int kk = 0; kk < 4; ++kk) qf[kk] = *(const bf16x8*)(qbase + kk * 32);
  }
  float rs[4] = {0.f, 0.f, 0.f, 0.f};  // lane-local sum of P (reduced in epilogue)
  f32x4 oacc[8] = {};
  const float scale = 0.08838834764831845f;  // 1/sqrt(128)
  u16* pb = pbuf[w];

  __syncthreads();  // drain prologue staging of buf0

  for (int si = 0; si < nsel; ++si) {
    int cur = si & 1;
    if (si + 1 < nsel) {  // prefetch next K AND V; drained at end-of-iter barrier
      stageK(1 - cur, selrow[si + 1]);
      stageV(1 - cur, selrow[si + 1]);
    }

    f32x4 sacc[4] = {};
#pragma unroll
    for (int kk = 0; kk < 4; ++kk) {
#pragma unroll
      for (int nt = 0; nt < 4; ++nt) {
        int row = nt * 16 + l16;
        bf16x8 bfr = *(const bf16x8*)(&Ks[cur][(row * 16 + ((kk * 4 + quad) ^ l16)) * 8]);
        sacc[nt] = __builtin_amdgcn_mfma_f32_16x16x32_bf16(qf[kk], bfr, sacc[nt], 0, 0, 0);
      }
    }
    // P = exp(s*scale), bf16-rounded; C-layout -> pbuf rows; track row sums
#pragma unroll
    for (int nt = 0; nt < 4; ++nt) {
#pragma unroll
      for (int p = 0; p < 4; ++p) {
        float pv = __expf(sacc[nt][p] * scale);
        u16 pr = f2bf(pv);
        int row = quad * 4 + p, col = nt * 16 + l16;
        pb[row * 64 + (((col >> 3) ^ (row & 7)) << 3) + (col & 7)] = pr;
        rs[p] += bf2f(pr);  // l consistent with rounded P
      }
    }
    // same-wave LDS write->read fence (pbuf wave-private; no cross-wave barrier)
    asm volatile("s_waitcnt lgkmcnt(0)" ::: "memory");
#pragma unroll
    for (int ks2 = 0; ks2 < 2; ++ks2) {
      bf16x8 pf = *(const bf16x8*)(pb + l16 * 64 + (((ks2 * 4 + quad) ^ (l16 & 7)) << 3));
#pragma unroll
      for (int nt = 0; nt < 8; ++nt) {
        int d = nt * 16 + l16;
        bf16x8 vf = *(const bf16x8*)(&Vs[cur][(d * 8 + ((ks2 * 4 + quad) ^ (d & 7))) * 8]);
        oacc[nt] = __builtin_amdgcn_mfma_f32_16x16x32_bf16(pf, vf, oacc[nt], 0, 0, 0);
      }
    }
    __syncthreads();  // single barrier/iter: drains next-buf staging (issued a
                      // full iter ago) + orders buf(cur) reads before reuse
  }
  // epilogue: reduce rs over the 16 lanes of each quad-group
#pragma unroll
  for (int p = 0; p < 4; ++p)
#pragma unroll
    for (int off = 1; off < 16; off <<= 1)
      rs[p] += __shfl_xor(rs[p], off, 64);
  float cntm = (float)(64 * (NB - nsel));  // masked cols contribute exp(0)=1 each
#pragma unroll
  for (int p = 0; p < 4; ++p) {
    float inv = 1.0f / (rs[p] + cntm);
    int row = qb * 64 + w * 16 + quad * 4 + p;
#pragma unroll
    for (int nt = 0; nt < 8; ++nt) {
      float o = (oacc[nt][p] + vc[nt]) * inv;
      attnb[(size_t)row * DMODEL + h * HD + nt * 16 + l16] = f2bf(o);
    }
  }
}

extern "C" void kernel_launch(void* const* d_in, const int* in_sizes, int n_in,
                              void* d_out, int out_size, void* d_ws, size_t ws_size,
                              hipStream_t stream) {
  const float* hidden = (const float*)d_in[0];
  const float* q_w = (const float*)d_in[1];
  const float* k_w = (const float*)d_in[2];
  const float* v_w = (const float*)d_in[3];
  const float* o_w = (const float*)d_in[4];
  const float* sp  = (const float*)d_in[5];

  char* ws = (char*)d_ws;
  size_t off = 0;
  auto alloc = [&](size_t bytes) -> void* {
    void* p = ws + off;
    off += (bytes + 255) & ~(size_t)255;
    return p;
  };
  u16* Xb     = (u16*)alloc((size_t)SEQ * DMODEL * 2);          // 8 MB (reused as attnb)
  u16* Wqkvt  = (u16*)alloc((size_t)NQKV * DMODEL * 2);         // 25 MB
  u16* Wot    = (u16*)alloc((size_t)DMODEL * DMODEL * 2);       // 8 MB
  u16* QKVb   = (u16*)alloc((size_t)SEQ * NQKV * 2);            // 25 MB
  u16* Qh     = (u16*)alloc((size_t)NH * SEQ * HD * 2);         // 8 MB
  u16* Kh     = (u16*)alloc((size_t)NH * SEQ * HD * 2);         // 8 MB
  u16* Vt     = (u16*)alloc((size_t)NH * HD * SEQ * 2);         // 8 MB
  float* Vbsum = (float*)alloc((size_t)NH * NB * HD * 4);       // 256 KB
  int* sel_cnt = (int*)alloc(NH * NB * 4);
  int* sel_idx = (int*)alloc(NH * NB * NB * 4);
  unsigned* sel_mask = (unsigned*)alloc(NH * NB * 4);
  u16* attnb = Xb;  // Xb dead after QKV GEMM; attnb written after -> safe alias

  pre_kernel<<<3088, 256, 0, stream>>>(hidden, q_w, k_w, v_w, o_w, sp,
                                       Xb, Wqkvt, Wot, sel_cnt, sel_idx, sel_mask);
  gemm_bt_kernel<1><<<dim3(NQKV / 128, SEQ / 128), 256, 0, stream>>>(
      Xb, Wqkvt, QKVb, SEQ, NQKV, DMODEL);
  prep_kernel<<<dim3(NB, NH), 256, 0, stream>>>(QKVb, Qh, Kh, Vt, Vbsum);
  attn_kernel<<<512, 256, 0, stream>>>(Qh, Kh, Vt, Vbsum, sel_cnt, sel_idx,
                                       sel_mask, attnb);
  gemm_bt_kernel<0><<<dim3(DMODEL / 128, SEQ / 128), 256, 0, stream>>>(
      attnb, Wot, d_out, SEQ, DMODEL, DMODEL);
}

// Round 6
// 275.628 us; speedup vs baseline: 1.2095x; 1.0501x over previous
//
#include <hip/hip_runtime.h>
#include <hip/hip_bf16.h>
#include <cstdint>
#include <cstddef>

typedef __bf16 bf16x8 __attribute__((ext_vector_type(8)));
typedef float f32x4 __attribute__((ext_vector_type(4)));
typedef unsigned short u16;

#define SEQ 2048
#define NH 16
#define HD 128
#define DMODEL 2048
#define NQKV 6144
#define NB 32     // seq blocks (2048/64)
#define KSEL 512  // top-k blocks per head

__device__ __forceinline__ u16 f2bf(float f) {
  unsigned u = __float_as_uint(f);
  u += 0x7fffu + ((u >> 16) & 1u);  // round-to-nearest-even
  return (u16)(u >> 16);
}
__device__ __forceinline__ float bf2f(u16 b) {
  return __uint_as_float(((unsigned)b) << 16);
}

// Async global->LDS, 16B per lane. LDS dest = wave-uniform base + lane*16.
__device__ __forceinline__ void async_copy16(const void* g, void* l) {
  __builtin_amdgcn_global_load_lds(
      (__attribute__((address_space(1))) void*)(unsigned long long)g,
      (__attribute__((address_space(3))) void*)(unsigned)(unsigned long long)l,
      16, 0, 0);
}

// ---------------- fused pre-pass v3 ----------------
// bid 0..15: mask (serial rank-count, FIRST so it hides under BW work)
// bid 16..31: RoPE cos/sin table (2048 x 64 float2, accurate sincosf)
// bid 32..1055: convert hidden fp32->bf16
// bid 1056..3103: weight transposes (2 tiles/block, ushort4 writes)
__global__ __launch_bounds__(256) void pre_kernel(
    const float* __restrict__ hidden, const float* __restrict__ qw,
    const float* __restrict__ kw, const float* __restrict__ vw,
    const float* __restrict__ ow, const float* __restrict__ sp,
    u16* __restrict__ Xb, u16* __restrict__ Wqkvt, u16* __restrict__ Wot,
    int* __restrict__ sel_cnt, int* __restrict__ sel_idx, unsigned* __restrict__ sel_mask,
    float2* __restrict__ sctab) {
  __shared__ __align__(16) char smem[64 * 65 * 4];
  int bid = blockIdx.x, t = threadIdx.x;
  if (bid < 16) {  // mask: per-head top-512 by rank counting
    int h = bid;
    float* vals = (float*)smem;
    unsigned char* selb = (unsigned char*)(smem + 4096);
    for (int i = 0; i < 4; ++i) vals[t + i * 256] = sp[h * 1024 + t + i * 256];
    __syncthreads();
    for (int i = 0; i < 4; ++i) {
      float v = vals[t + i * 256];
      int cnt = 0;
      for (int j = 0; j < 1024; ++j) cnt += vals[j] > v ? 1 : 0;
      selb[t + i * 256] = (cnt < (KSEL - 1)) ? 1 : 0;  // rank<511 <=> strictly > thresh
    }
    __syncthreads();
    if (t < NB) {
      int n = 0; unsigned m = 0;
      for (int kb = 0; kb < NB; ++kb) {
        if (selb[t * NB + kb]) { sel_idx[(h * NB + t) * NB + n] = kb; ++n; m |= 1u << kb; }
      }
      sel_cnt[h * NB + t] = n;
      sel_mask[h * NB + t] = m;
    }
    return;
  }
  if (bid < 32) {  // cos/sin table: same powf/sincosf numerics as the old prep
    int b = bid - 16;  // 128 s-rows per block
    for (int i = 0; i < 32; ++i) {
      int idx = i * 256 + t;
      int s = b * 128 + (idx >> 6), j = idx & 63;
      float inv = powf(10000.0f, -(float)j / 64.0f);
      float sn, cs;
      sincosf((float)s * inv, &sn, &cs);
      sctab[s * 64 + j] = make_float2(cs, sn);
    }
    return;
  }
  if (bid < 1056) {  // convert: 2048x2048 fp32 -> bf16, 4 independent float4/thread
    int base = (bid - 32) * 1024 + t;
    float4 v0 = ((const float4*)hidden)[base];
    float4 v1 = ((const float4*)hidden)[base + 256];
    float4 v2 = ((const float4*)hidden)[base + 512];
    float4 v3 = ((const float4*)hidden)[base + 768];
    ((ushort4*)Xb)[base]       = make_ushort4(f2bf(v0.x), f2bf(v0.y), f2bf(v0.z), f2bf(v0.w));
    ((ushort4*)Xb)[base + 256] = make_ushort4(f2bf(v1.x), f2bf(v1.y), f2bf(v1.z), f2bf(v1.w));
    ((ushort4*)Xb)[base + 512] = make_ushort4(f2bf(v2.x), f2bf(v2.y), f2bf(v2.z), f2bf(v2.w));
    ((ushort4*)Xb)[base + 768] = make_ushort4(f2bf(v3.x), f2bf(v3.y), f2bf(v3.z), f2bf(v3.w));
    return;
  }
  // transpose+convert: 2 64x64 tiles per block
  float(*tile)[65] = (float(*)[65])smem;  // pad 65: both phases <=2-way bank alias
  for (int ti = 0; ti < 2; ++ti) {
    int tidx = (bid - 1056) * 2 + ti;  // 0..4095
    int wsel = tidx >> 10, rem = tidx & 1023, bx = rem & 31, by = rem >> 5;
    const float* in = (wsel == 0) ? qw : (wsel == 1) ? kw : (wsel == 2) ? vw : ow;
    u16* out = (wsel == 3) ? Wot : Wqkvt + (size_t)wsel * DMODEL * 2048;
    int c0 = bx * 64, r0 = by * 64;
    if (ti) __syncthreads();  // tile reuse fence
#pragma unroll
    for (int i = 0; i < 4; ++i) {  // read: float4-coalesced
      int chunk = i * 256 + t, r = chunk >> 4, c4 = chunk & 15;
      float4 v = *(const float4*)(in + (size_t)(r0 + r) * 2048 + c0 + c4 * 4);
      tile[r][c4 * 4 + 0] = v.x; tile[r][c4 * 4 + 1] = v.y;
      tile[r][c4 * 4 + 2] = v.z; tile[r][c4 * 4 + 3] = v.w;
    }
    __syncthreads();
#pragma unroll
    for (int i = 0; i < 4; ++i) {  // write: ushort4-coalesced
      int item = i * 256 + t, cc = item >> 4, rr4 = item & 15;
      ushort4 o = make_ushort4(f2bf(tile[rr4 * 4 + 0][cc]), f2bf(tile[rr4 * 4 + 1][cc]),
                               f2bf(tile[rr4 * 4 + 2][cc]), f2bf(tile[rr4 * 4 + 3][cc]));
      *(ushort4*)(out + (size_t)(c0 + cc) * 2048 + r0 + rr4 * 4) = o;
    }
  }
}

// ---------------- bf16 GEMM: C[m][n] = sum_k A[m][k] * Bt[n][k] ----------------
// m97 structure: 128x128 tile, BK=64, global_load_lds width=16, XOR-swizzled LDS.
// Wave n-tile map INTERLEAVED: ntoff = (w&1)*32 + (nt&1)*16 + (nt>>1)*64, so the
// RoPE pair (d, d+64) sits in the same thread (nt <-> nt+2) for MODE 2.
// MODE 0: plain fp32 store. MODE 1: fp32 atomicAdd (split-K via blockIdx.z).
// MODE 2: fused QKV epilogue -> RoPE'd Qh/Kh, transposed Vt, Vbsum. No C write.
template <int MODE>
__global__ __launch_bounds__(256, 2) void gemm_bt_kernel(
    const u16* __restrict__ A, const u16* __restrict__ Bt, void* __restrict__ Cout,
    int M, int N, int K, const float2* __restrict__ sctab,
    u16* __restrict__ Qh, u16* __restrict__ Kh, u16* __restrict__ Vt,
    float* __restrict__ Vbsum) {
  __shared__ __align__(16) u16 As[8192];  // 128 rows x 64 elems, swizzled
  __shared__ __align__(16) u16 Bs[8192];
  const int t = threadIdx.x;
  const int lane = t & 63, w = t >> 6;
  const int wm = (w >> 1) * 64;
  const int quad = lane >> 4, l16 = lane & 15;
  const int m0 = blockIdx.y * 128, n0 = blockIdx.x * 128;
  const int ksplit = K / gridDim.z, kbeg = blockIdx.z * ksplit;

  f32x4 acc[4][4] = {};

  for (int kt = kbeg; kt < kbeg + ksplit; kt += 64) {
    __syncthreads();  // previous iter's frag reads done before restaging
#pragma unroll
    for (int j = 0; j < 4; ++j) {
      int sl = w * 256 + j * 64 + lane;
      int row = sl >> 3, c = (sl & 7) ^ (row & 7);
      const u16* ga = A + (size_t)(m0 + row) * K + kt + c * 8;
      const u16* gb = Bt + (size_t)(n0 + row) * K + kt + c * 8;
      async_copy16(ga, &As[(size_t)(w * 256 + j * 64) * 8]);
      async_copy16(gb, &Bs[(size_t)(w * 256 + j * 64) * 8]);
    }
    __syncthreads();  // vmcnt(0) drain -> tile visible
#pragma unroll
    for (int ks = 0; ks < 2; ++ks) {
      bf16x8 af[4], bfr[4];
#pragma unroll
      for (int mt = 0; mt < 4; ++mt) {
        int row = wm + mt * 16 + l16;
        af[mt] = *(const bf16x8*)(&As[(row * 8 + ((ks * 4 + quad) ^ (l16 & 7))) * 8]);
      }
#pragma unroll
      for (int nt = 0; nt < 4; ++nt) {
        int row = (w & 1) * 32 + (nt & 1) * 16 + (nt >> 1) * 64 + l16;
        bfr[nt] = *(const bf16x8*)(&Bs[(row * 8 + ((ks * 4 + quad) ^ (l16 & 7))) * 8]);
      }
#pragma unroll
      for (int mt = 0; mt < 4; ++mt)
#pragma unroll
        for (int nt = 0; nt < 4; ++nt)
          acc[mt][nt] = __builtin_amdgcn_mfma_f32_16x16x32_bf16(af[mt], bfr[nt], acc[mt][nt], 0, 0, 0);
    }
  }
  // C/D layout: col=lane&15, row=quad*4+reg (m89-verified)
  if (MODE < 2) {
#pragma unroll
    for (int mt = 0; mt < 4; ++mt)
#pragma unroll
      for (int nt = 0; nt < 4; ++nt) {
        int coff = n0 + (w & 1) * 32 + (nt & 1) * 16 + (nt >> 1) * 64 + l16;
#pragma unroll
        for (int p = 0; p < 4; ++p) {
          int row = m0 + wm + mt * 16 + quad * 4 + p;
          if (MODE == 0)
            ((float*)Cout)[(size_t)row * N + coff] = acc[mt][nt][p];
          else
            unsafeAtomicAdd(&((float*)Cout)[(size_t)row * N + coff], acc[mt][nt][p]);
        }
      }
    return;
  }
  // MODE 2: fused QKV epilogue. Each n-block = one head's full 128-d.
  int wsel = n0 >> 11;       // 0=Q, 1=K, 2=V
  int h = (n0 >> 7) & 15;
  if (wsel < 2) {
    u16* dst = wsel ? Kh : Qh;
#pragma unroll
    for (int mt = 0; mt < 4; ++mt)
#pragma unroll
      for (int p = 0; p < 4; ++p) {
        int s = m0 + wm + mt * 16 + quad * 4 + p;
        const float2* trow = sctab + s * 64;
        u16* drow = dst + ((size_t)h * SEQ + s) * HD;
#pragma unroll
        for (int nt = 0; nt < 2; ++nt) {
          int j = (w & 1) * 32 + nt * 16 + l16;  // d < 64; pair at d+64 is nt+2
          float2 cs = trow[j];
          float lo = acc[mt][nt][p], hi = acc[mt][nt + 2][p];
          drow[j]      = f2bf(lo * cs.x - hi * cs.y);
          drow[j + 64] = f2bf(hi * cs.x + lo * cs.y);
        }
      }
  } else {
    int sb = (m0 >> 6) + (wm >> 6);  // this wave's 64-row s-block
#pragma unroll
    for (int nt = 0; nt < 4; ++nt) {
      int d = (w & 1) * 32 + (nt & 1) * 16 + (nt >> 1) * 64 + l16;
      u16* vrow = Vt + ((size_t)h * HD + d) * SEQ;
      float bsum = 0.f;
#pragma unroll
      for (int mt = 0; mt < 4; ++mt)
#pragma unroll
        for (int p = 0; p < 4; ++p) {
          int s = m0 + wm + mt * 16 + quad * 4 + p;
          float v = acc[mt][nt][p];
          vrow[s] = f2bf(v);
          bsum += v;
        }
      bsum += __shfl_xor(bsum, 16, 64);  // reduce over quads -> sum of 64 s
      bsum += __shfl_xor(bsum, 32, 64);
      if (quad == 0) Vbsum[((size_t)h * NB + sb) * HD + d] = bsum;
    }
  }
}

// ---------------- block-sparse attention v4: full software pipeline ----------------
// Softmax-lite (m=0 fixed, exact); masked-zero correction in epilogue.
// K AND V double-buffered, ONE barrier per iteration.
// LDS = 2*16K + 2*16K + 8K = 72 KB -> 2 WGs/CU = full co-residency of 512 WGs.
__global__ __launch_bounds__(256, 2) void attn_kernel(
    const u16* __restrict__ Qh, const u16* __restrict__ Kh, const u16* __restrict__ Vt,
    const float* __restrict__ Vbsum, const int* __restrict__ sel_cnt,
    const int* __restrict__ sel_idx, const unsigned* __restrict__ sel_mask,
    u16* __restrict__ attnb) {
  __shared__ __align__(16) u16 Ks[2][8192];    // 64 k-rows x 128 d (16 chunks), c^(r&15)
  __shared__ __align__(16) u16 Vs[2][8192];    // 128 d-rows x 64 s (8 chunks), c^(d&7)
  __shared__ __align__(16) u16 pbuf[4][1024];  // per-wave 16x64, chunk-swizzle c^(row&7)
  // XCD swizzle: 2 heads per XCD -> per-XCD K/V working set 2MB <= 4MB L2.
  int bid = blockIdx.x;
  int h = (bid & 7) * 2 + ((bid >> 3) >> 5);
  int qb = (bid >> 3) & 31;
  int t = threadIdx.x, lane = t & 63, w = t >> 6;
  int quad = lane >> 4, l16 = lane & 15;
  int rowblk = h * NB + qb;
  int nsel = sel_cnt[rowblk];
  unsigned smask = sel_mask[rowblk];
  const int* selrow = sel_idx + rowblk * NB;

  auto stageK = [&](int buf, int kb) {
    const u16* kbase = Kh + ((size_t)h * SEQ + kb * 64) * HD;
#pragma unroll
    for (int j = 0; j < 4; ++j) {
      int s = w * 256 + j * 64 + lane;
      int r = s >> 4, c = (s & 15) ^ (r & 15);
      async_copy16(kbase + (size_t)r * HD + c * 8, &Ks[buf][(w * 256 + j * 64) * 8]);
    }
  };
  auto stageV = [&](int buf, int kb) {
    const u16* vbase = Vt + (size_t)h * HD * SEQ + kb * 64;
#pragma unroll
    for (int j = 0; j < 4; ++j) {
      int s = w * 256 + j * 64 + lane;
      int d = s >> 3, c = (s & 7) ^ (d & 7);
      async_copy16(vbase + (size_t)d * SEQ + c * 8, &Vs[buf][(w * 256 + j * 64) * 8]);
    }
  };

  if (nsel > 0) { stageK(0, selrow[0]); stageV(0, selrow[0]); }

  // vcorr in registers: sum of unselected V-block sums at this lane's 8 d-slots
  float vc[8] = {};
  for (int kb = 0; kb < NB; ++kb)
    if (!((smask >> kb) & 1u)) {
      const float* vb = Vbsum + ((size_t)h * NB + kb) * HD + l16;
#pragma unroll
      for (int nt = 0; nt < 8; ++nt) vc[nt] += vb[nt * 16];
    }
  // Q fragments: A-layout m=lane&15, k=quad*8+j (4 k-steps of 32)
  bf16x8 qf[4];
  {
    const u16* qbase = Qh + ((size_t)h * SEQ + qb * 64 + w * 16 + l16) * HD + quad * 8;
#pragma unroll
    for (int kk = 0; kk < 4; ++kk) qf[kk] = *(const bf16x8*)(qbase + kk * 32);
  }
  float rs[4] = {0.f, 0.f, 0.f, 0.f};  // lane-local sum of P (reduced in epilogue)
  f32x4 oacc[8] = {};
  const float scale = 0.08838834764831845f;  // 1/sqrt(128)
  u16* pb = pbuf[w];

  __syncthreads();  // drain prologue staging of buf0

  for (int si = 0; si < nsel; ++si) {
    int cur = si & 1;
    if (si + 1 < nsel) {  // prefetch next K AND V; drained at end-of-iter barrier
      stageK(1 - cur, selrow[si + 1]);
      stageV(1 - cur, selrow[si + 1]);
    }

    f32x4 sacc[4] = {};
#pragma unroll
    for (int kk = 0; kk < 4; ++kk) {
#pragma unroll
      for (int nt = 0; nt < 4; ++nt) {
        int row = nt * 16 + l16;
        bf16x8 bfr = *(const bf16x8*)(&Ks[cur][(row * 16 + ((kk * 4 + quad) ^ l16)) * 8]);
        sacc[nt] = __builtin_amdgcn_mfma_f32_16x16x32_bf16(qf[kk], bfr, sacc[nt], 0, 0, 0);
      }
    }
    // P = exp(s*scale), bf16-rounded; C-layout -> pbuf rows; track row sums
#pragma unroll
    for (int nt = 0; nt < 4; ++nt) {
#pragma unroll
      for (int p = 0; p < 4; ++p) {
        float pv = __expf(sacc[nt][p] * scale);
        u16 pr = f2bf(pv);
        int row = quad * 4 + p, col = nt * 16 + l16;
        pb[row * 64 + (((col >> 3) ^ (row & 7)) << 3) + (col & 7)] = pr;
        rs[p] += bf2f(pr);  // l consistent with rounded P
      }
    }
    // same-wave LDS write->read fence (pbuf wave-private; no cross-wave barrier)
    asm volatile("s_waitcnt lgkmcnt(0)" ::: "memory");
#pragma unroll
    for (int ks2 = 0; ks2 < 2; ++ks2) {
      bf16x8 pf = *(const bf16x8*)(pb + l16 * 64 + (((ks2 * 4 + quad) ^ (l16 & 7)) << 3));
#pragma unroll
      for (int nt = 0; nt < 8; ++nt) {
        int d = nt * 16 + l16;
        bf16x8 vf = *(const bf16x8*)(&Vs[cur][(d * 8 + ((ks2 * 4 + quad) ^ (d & 7))) * 8]);
        oacc[nt] = __builtin_amdgcn_mfma_f32_16x16x32_bf16(pf, vf, oacc[nt], 0, 0, 0);
      }
    }
    __syncthreads();  // single barrier/iter: drains next-buf staging (issued a
                      // full iter ago) + orders buf(cur) reads before reuse
  }
  // epilogue: reduce rs over the 16 lanes of each quad-group
#pragma unroll
  for (int p = 0; p < 4; ++p)
#pragma unroll
    for (int off = 1; off < 16; off <<= 1)
      rs[p] += __shfl_xor(rs[p], off, 64);
  float cntm = (float)(64 * (NB - nsel));  // masked cols contribute exp(0)=1 each
#pragma unroll
  for (int p = 0; p < 4; ++p) {
    float inv = 1.0f / (rs[p] + cntm);
    int row = qb * 64 + w * 16 + quad * 4 + p;
#pragma unroll
    for (int nt = 0; nt < 8; ++nt) {
      float o = (oacc[nt][p] + vc[nt]) * inv;
      attnb[(size_t)row * DMODEL + h * HD + nt * 16 + l16] = f2bf(o);
    }
  }
}

extern "C" void kernel_launch(void* const* d_in, const int* in_sizes, int n_in,
                              void* d_out, int out_size, void* d_ws, size_t ws_size,
                              hipStream_t stream) {
  const float* hidden = (const float*)d_in[0];
  const float* q_w = (const float*)d_in[1];
  const float* k_w = (const float*)d_in[2];
  const float* v_w = (const float*)d_in[3];
  const float* o_w = (const float*)d_in[4];
  const float* sp  = (const float*)d_in[5];

  char* ws = (char*)d_ws;
  size_t off = 0;
  auto alloc = [&](size_t bytes) -> void* {
    void* p = ws + off;
    off += (bytes + 255) & ~(size_t)255;
    return p;
  };
  u16* Xb     = (u16*)alloc((size_t)SEQ * DMODEL * 2);          // 8 MB (reused as attnb)
  u16* Wqkvt  = (u16*)alloc((size_t)NQKV * DMODEL * 2);         // 25 MB
  u16* Wot    = (u16*)alloc((size_t)DMODEL * DMODEL * 2);       // 8 MB
  u16* Qh     = (u16*)alloc((size_t)NH * SEQ * HD * 2);         // 8 MB
  u16* Kh     = (u16*)alloc((size_t)NH * SEQ * HD * 2);         // 8 MB
  u16* Vt     = (u16*)alloc((size_t)NH * HD * SEQ * 2);         // 8 MB
  float* Vbsum = (float*)alloc((size_t)NH * NB * HD * 4);       // 256 KB
  float2* sctab = (float2*)alloc((size_t)SEQ * 64 * 8);         // 1 MB cos/sin
  int* sel_cnt = (int*)alloc(NH * NB * 4);
  int* sel_idx = (int*)alloc(NH * NB * NB * 4);
  unsigned* sel_mask = (unsigned*)alloc(NH * NB * 4);
  u16* attnb = Xb;  // Xb dead after QKV GEMM; attnb written after -> safe alias

  hipMemsetAsync(d_out, 0, (size_t)SEQ * DMODEL * 4, stream);  // split-K accum base

  pre_kernel<<<3104, 256, 0, stream>>>(hidden, q_w, k_w, v_w, o_w, sp,
                                       Xb, Wqkvt, Wot, sel_cnt, sel_idx, sel_mask, sctab);
  // QKV GEMM with fused RoPE/transpose/Vbsum epilogue (prep_kernel eliminated)
  gemm_bt_kernel<2><<<dim3(NQKV / 128, SEQ / 128, 1), 256, 0, stream>>>(
      Xb, Wqkvt, nullptr, SEQ, NQKV, DMODEL, sctab, Qh, Kh, Vt, Vbsum);
  attn_kernel<<<512, 256, 0, stream>>>(Qh, Kh, Vt, Vbsum, sel_cnt, sel_idx,
                                       sel_mask, attnb);
  // proj GEMM: split-K=2 -> 512 blocks (2 WG/CU co-residency), fp32 atomic accum
  gemm_bt_kernel<1><<<dim3(DMODEL / 128, SEQ / 128, 2), 256, 0, stream>>>(
      attnb, Wot, d_out, SEQ, DMODEL, DMODEL, nullptr, nullptr, nullptr, nullptr, nullptr);
}